// Round 5
// baseline (1671.740 us; speedup 1.0000x reference)
//
#include <hip/hip_runtime.h>
#include <hip/hip_bf16.h>
#include <hip/hip_cooperative_groups.h>
#include <math.h>

namespace cg = cooperative_groups;

#define Nn 20000
#define Ee 640000
#define ETOT 660000   // Ee + Nn self loops
#define NF 512
#define C1 256        // HEADS*NHID
#define C2 64         // NOUT
#define KC 100
#define TEMP 5.0f
#define NSLOPE 0.2f
#define NPART 250     // blocks for cooperative clustering (250*80 = 20000 exactly)
#define CHB 80        // nodes per cluster block

typedef __attribute__((ext_vector_type(8))) short bf16x8;
typedef __attribute__((ext_vector_type(4))) float f32x4;

__device__ __forceinline__ float wredSum(float v) {
#pragma unroll
  for (int off = 32; off > 0; off >>= 1) v += __shfl_xor(v, off, 64);
  return v;
}
__device__ __forceinline__ float wredMax(float v) {
#pragma unroll
  for (int off = 32; off > 0; off >>= 1) v = fmaxf(v, __shfl_xor(v, off, 64));
  return v;
}
__device__ __forceinline__ ushort f2bf(float f) {
  __hip_bfloat16 b = __float2bfloat16(f);
  return *(ushort*)&b;
}
__device__ __forceinline__ float bf2f(ushort u) {
  __hip_bfloat16 b = *(__hip_bfloat16*)&u;
  return __bfloat162float(b);
}

// ---------------- CSR build ----------------
__global__ void hist_kernel(const int* __restrict__ ei, int* __restrict__ deg) {
  int e = blockIdx.x * 256 + threadIdx.x;
  if (e >= ETOT) return;
  int dst = e < Ee ? ei[Ee + e] : e - Ee;
  atomicAdd(&deg[dst], 1);
}

__global__ __launch_bounds__(1024) void scan2_kernel(const int* __restrict__ deg,
    int* __restrict__ rowp, int* __restrict__ curs) {
  __shared__ int wsum[16];
  __shared__ int wpre[16];
  int t = threadIdx.x;
  int lane = t & 63, w = t >> 6;
  int loc[20];
  int tot = 0;
  int base = t * 20;
  if (t < 1000) {
#pragma unroll
    for (int i = 0; i < 20; i++) { tot += deg[base + i]; loc[i] = tot; }
  }
  int s = tot;
#pragma unroll
  for (int off = 1; off < 64; off <<= 1) {
    int u = __shfl_up(s, off, 64);
    if (lane >= off) s += u;
  }
  if (lane == 63) wsum[w] = s;
  __syncthreads();
  if (t == 0) {
    int c = 0;
#pragma unroll
    for (int i = 0; i < 16; i++) { c += wsum[i]; wpre[i] = c; }
    rowp[0] = 0;
  }
  __syncthreads();
  int p = (w > 0 ? wpre[w - 1] : 0) + s - tot;
  if (t < 1000) {
    int prev = 0;
#pragma unroll
    for (int i = 0; i < 20; i++) {
      rowp[base + i + 1] = p + loc[i];
      curs[base + i] = p + prev;
      prev = loc[i];
    }
  }
}

__global__ void scatter_kernel(const int* __restrict__ ei, int* __restrict__ curs,
                               int* __restrict__ ssort, int* __restrict__ dsort) {
  int e = blockIdx.x * 256 + threadIdx.x;
  if (e >= ETOT) return;
  int src = e < Ee ? ei[e] : e - Ee;
  int dst = e < Ee ? ei[Ee + e] : e - Ee;
  int pos = atomicAdd(&curs[dst], 1);
  ssort[pos] = src;
  dsort[pos] = dst;
}

// ---------------- per-edge logits (LeakyReLU'd), CSR order ----------------
__global__ __launch_bounds__(256) void edge_e1(const int* __restrict__ ssort,
    const int* __restrict__ dsort, const float* __restrict__ asn,
    const float* __restrict__ adn, float2* __restrict__ eb) {
  int i = blockIdx.x * 256 + threadIdx.x;
  if (i >= ETOT) return;
  int s = ssort[i], d = dsort[i];
  float2 a = ((const float2*)asn)[s];
  float2 b = ((const float2*)adn)[d];
  float e0 = a.x + b.x, e1 = a.y + b.y;
  e0 = e0 > 0.f ? e0 : NSLOPE * e0;
  e1 = e1 > 0.f ? e1 : NSLOPE * e1;
  eb[i] = make_float2(e0, e1);
}

__global__ __launch_bounds__(256) void edge_e2(const int* __restrict__ ssort,
    const int* __restrict__ dsort, const float* __restrict__ asn,
    const float* __restrict__ adn, float* __restrict__ eb) {
  int i = blockIdx.x * 256 + threadIdx.x;
  if (i >= ETOT) return;
  float e = asn[ssort[i]] + adn[dsort[i]];
  eb[i] = e > 0.f ? e : NSLOPE * e;
}

// ---------------- GEMM1 via split-bf16 MFMA (3-pass Markidis) ----------------
// C[20000,256] = A[20000,512] @ B[256,512]^T, f32-grade accuracy.
// On-the-fly split in staging: x = hi + lo (both bf16); C = Ah*Bh + Ah*Bl + Al*Bh.
__global__ __launch_bounds__(256) void gemm1_mfma(const float* __restrict__ A,
    const float* __restrict__ B, float* __restrict__ C) {
  __shared__ ushort Ah[128 * 40], Al[128 * 40], Bh[128 * 40], Bl[128 * 40];
  int tid = threadIdx.x;
  int bm = blockIdx.x << 7, bn = blockIdx.y << 7;
  int w = tid >> 6, lane = tid & 63;
  int wm = (w >> 1) << 6, wn = (w & 1) << 6;
  int fr = lane & 15, ko = (lane >> 4) << 3;   // frag row/col, k-offset (8 elems)
  f32x4 acc[4][4] = {};
  for (int k0 = 0; k0 < 512; k0 += 32) {
    __syncthreads();
#pragma unroll
    for (int cc = 0; cc < 4; cc++) {
      int c = tid + (cc << 8);
      int row = c >> 3, q = c & 7;
      int off = row * 40 + (q << 2);
      int gr = bm + row;
      float4 va = (gr < Nn) ? *(const float4*)(A + (size_t)gr * NF + k0 + (q << 2))
                            : make_float4(0.f, 0.f, 0.f, 0.f);
      float4 vb = *(const float4*)(B + (size_t)(bn + row) * NF + k0 + (q << 2));
      ushort h0 = f2bf(va.x), h1 = f2bf(va.y), h2 = f2bf(va.z), h3 = f2bf(va.w);
      *(ushort4*)&Ah[off] = make_ushort4(h0, h1, h2, h3);
      *(ushort4*)&Al[off] = make_ushort4(
          f2bf(va.x - bf2f(h0)), f2bf(va.y - bf2f(h1)),
          f2bf(va.z - bf2f(h2)), f2bf(va.w - bf2f(h3)));
      ushort g0 = f2bf(vb.x), g1 = f2bf(vb.y), g2 = f2bf(vb.z), g3 = f2bf(vb.w);
      *(ushort4*)&Bh[off] = make_ushort4(g0, g1, g2, g3);
      *(ushort4*)&Bl[off] = make_ushort4(
          f2bf(vb.x - bf2f(g0)), f2bf(vb.y - bf2f(g1)),
          f2bf(vb.z - bf2f(g2)), f2bf(vb.w - bf2f(g3)));
    }
    __syncthreads();
    bf16x8 aH[4], bH[4], t[4];
#pragma unroll
    for (int mf = 0; mf < 4; mf++)
      aH[mf] = *(const bf16x8*)&Ah[(wm + (mf << 4) + fr) * 40 + ko];
#pragma unroll
    for (int nf = 0; nf < 4; nf++)
      bH[nf] = *(const bf16x8*)&Bh[(wn + (nf << 4) + fr) * 40 + ko];
#pragma unroll
    for (int mf = 0; mf < 4; mf++)
#pragma unroll
      for (int nf = 0; nf < 4; nf++)
        acc[mf][nf] = __builtin_amdgcn_mfma_f32_16x16x32_bf16(aH[mf], bH[nf], acc[mf][nf], 0, 0, 0);
#pragma unroll
    for (int nf = 0; nf < 4; nf++)
      t[nf] = *(const bf16x8*)&Bl[(wn + (nf << 4) + fr) * 40 + ko];
#pragma unroll
    for (int mf = 0; mf < 4; mf++)
#pragma unroll
      for (int nf = 0; nf < 4; nf++)
        acc[mf][nf] = __builtin_amdgcn_mfma_f32_16x16x32_bf16(aH[mf], t[nf], acc[mf][nf], 0, 0, 0);
#pragma unroll
    for (int mf = 0; mf < 4; mf++)
      t[mf] = *(const bf16x8*)&Al[(wm + (mf << 4) + fr) * 40 + ko];
#pragma unroll
    for (int mf = 0; mf < 4; mf++)
#pragma unroll
      for (int nf = 0; nf < 4; nf++)
        acc[mf][nf] = __builtin_amdgcn_mfma_f32_16x16x32_bf16(t[mf], bH[nf], acc[mf][nf], 0, 0, 0);
  }
  int cr = (lane >> 4) << 2, cc2 = lane & 15;
#pragma unroll
  for (int mf = 0; mf < 4; mf++) {
#pragma unroll
    for (int r = 0; r < 4; r++) {
      int row = bm + wm + (mf << 4) + cr + r;
      if (row < Nn) {
#pragma unroll
        for (int nf = 0; nf < 4; nf++)
          C[(size_t)row * C1 + bn + wn + (nf << 4) + cc2] = acc[mf][nf][r];
      }
    }
  }
}

// ---------------- f32 GEMM 64x64 (GEMM2, N=64) ----------------
__global__ __launch_bounds__(256) void gemm_nt(const float* __restrict__ A,
    const float* __restrict__ B, float* __restrict__ C, int M, int N, int K) {
  __shared__ __align__(16) float As[16][68];
  __shared__ __align__(16) float Bs[16][68];
  int tid = threadIdx.x;
  int bm = blockIdx.x << 6, bn = blockIdx.y << 6;
  int lr = tid >> 2;
  int lc = (tid & 3) << 2;
  int tx = tid & 15, ty = tid >> 4;
  float acc[4][4] = {};
  for (int k0 = 0; k0 < K; k0 += 16) {
    int am = bm + lr;
    float4 av = make_float4(0.f, 0.f, 0.f, 0.f);
    if (am < M) av = *(const float4*)(A + (size_t)am * K + k0 + lc);
    float4 bv = *(const float4*)(B + (size_t)(bn + lr) * K + k0 + lc);
    __syncthreads();
    As[lc + 0][lr] = av.x; As[lc + 1][lr] = av.y; As[lc + 2][lr] = av.z; As[lc + 3][lr] = av.w;
    Bs[lc + 0][lr] = bv.x; Bs[lc + 1][lr] = bv.y; Bs[lc + 2][lr] = bv.z; Bs[lc + 3][lr] = bv.w;
    __syncthreads();
#pragma unroll
    for (int k = 0; k < 16; k++) {
      float4 a = *(const float4*)&As[k][ty << 2];
      float4 b = *(const float4*)&Bs[k][tx << 2];
      float aa[4] = {a.x, a.y, a.z, a.w};
      float bb[4] = {b.x, b.y, b.z, b.w};
#pragma unroll
      for (int i = 0; i < 4; i++)
#pragma unroll
        for (int j = 0; j < 4; j++) acc[i][j] += aa[i] * bb[j];
    }
  }
#pragma unroll
  for (int i = 0; i < 4; i++) {
    int row = bm + (ty << 2) + i;
    if (row < M) {
#pragma unroll
      for (int j = 0; j < 4; j++)
        C[(size_t)row * N + bn + (tx << 2) + j] = acc[i][j];
    }
  }
}

// ---------------- per-node attention scalars ----------------
__global__ __launch_bounds__(256) void alpha1_kernel(const float* __restrict__ h,
    const float* __restrict__ a_src, const float* __restrict__ a_dst,
    float* __restrict__ asn, float* __restrict__ adn) {
  int l = threadIdx.x & 63;
  int n = (blockIdx.x << 2) + (threadIdx.x >> 6);
  if (n >= Nn) return;
  const float* hr = h + (size_t)n * C1;
  float h0 = hr[l], h1v = hr[64 + l], h2v = hr[128 + l], h3v = hr[192 + l];
  float ps0 = h0 * a_src[l] + h1v * a_src[64 + l];
  float pd0 = h0 * a_dst[l] + h1v * a_dst[64 + l];
  float ps1 = h2v * a_src[128 + l] + h3v * a_src[192 + l];
  float pd1 = h2v * a_dst[128 + l] + h3v * a_dst[192 + l];
  ps0 = wredSum(ps0); pd0 = wredSum(pd0); ps1 = wredSum(ps1); pd1 = wredSum(pd1);
  if (l == 0) {
    asn[2 * n] = ps0; asn[2 * n + 1] = ps1;
    adn[2 * n] = pd0; adn[2 * n + 1] = pd1;
  }
}

__global__ __launch_bounds__(256) void alpha2_kernel(const float* __restrict__ h,
    const float* __restrict__ a_src, const float* __restrict__ a_dst,
    float* __restrict__ asn, float* __restrict__ adn) {
  int l = threadIdx.x & 63;
  int n = (blockIdx.x << 2) + (threadIdx.x >> 6);
  if (n >= Nn) return;
  float v = h[(size_t)n * C2 + l];
  float ps = wredSum(v * a_src[l]);
  float pd = wredSum(v * a_dst[l]);
  if (l == 0) { asn[n] = ps; adn[n] = pd; }
}

// ---------------- layer 1: online segment softmax + float4 gather + ELU ----------------
__global__ __launch_bounds__(256) void agg1_kernel(const float* __restrict__ h,
    const float2* __restrict__ eb, const int* __restrict__ ssort,
    const float* __restrict__ b1, const int* __restrict__ rowp,
    float* __restrict__ ho) {
  __shared__ float redm[8], reds[8];
  __shared__ __align__(16) float slab[4][256];
  int n = blockIdx.x, tid = threadIdx.x;
  int w = tid >> 6, l = tid & 63;
  int lo = rowp[n], hi = rowp[n + 1];
  float m0 = -1e30f, s0 = 0.f, m1 = -1e30f, s1 = 0.f;
  for (int i = lo + tid; i < hi; i += 256) {
    float2 e = eb[i];
    if (e.x > m0) { s0 = s0 * __expf(m0 - e.x) + 1.f; m0 = e.x; }
    else s0 += __expf(e.x - m0);
    if (e.y > m1) { s1 = s1 * __expf(m1 - e.y) + 1.f; m1 = e.y; }
    else s1 += __expf(e.y - m1);
  }
#pragma unroll
  for (int off = 32; off > 0; off >>= 1) {
    float om = __shfl_xor(m0, off, 64), os = __shfl_xor(s0, off, 64);
    float nm = fmaxf(m0, om);
    s0 = s0 * __expf(m0 - nm) + os * __expf(om - nm); m0 = nm;
    om = __shfl_xor(m1, off, 64); os = __shfl_xor(s1, off, 64);
    nm = fmaxf(m1, om);
    s1 = s1 * __expf(m1 - nm) + os * __expf(om - nm); m1 = nm;
  }
  if (l == 0) { redm[w] = m0; reds[w] = s0; redm[4 + w] = m1; reds[4 + w] = s1; }
  __syncthreads();
  float M0 = fmaxf(fmaxf(redm[0], redm[1]), fmaxf(redm[2], redm[3]));
  float M1 = fmaxf(fmaxf(redm[4], redm[5]), fmaxf(redm[6], redm[7]));
  float S0 = reds[0] * __expf(redm[0] - M0) + reds[1] * __expf(redm[1] - M0)
           + reds[2] * __expf(redm[2] - M0) + reds[3] * __expf(redm[3] - M0);
  float S1 = reds[4] * __expf(redm[4] - M1) + reds[5] * __expf(redm[5] - M1)
           + reds[6] * __expf(redm[6] - M1) + reds[7] * __expf(redm[7] - M1);
  float inv0 = 1.f / (S0 + 1e-16f), inv1 = 1.f / (S1 + 1e-16f);
  const bool lo_head = (l < 32);
  float Msel = lo_head ? M0 : M1;
  float isel = lo_head ? inv0 : inv1;
  int ch = l << 2;
  int deg = hi - lo;
  float4 accA = {0.f, 0.f, 0.f, 0.f}, accB = {0.f, 0.f, 0.f, 0.f};
  int j = w;
  for (; j + 4 < deg; j += 8) {
    int i0 = lo + j, i1 = lo + j + 4;
    float2 eA = eb[i0];
    float2 eB = eb[i1];
    int sA = ssort[i0], sB = ssort[i1];
    float4 ha = *(const float4*)(h + (size_t)sA * C1 + ch);
    float4 hb = *(const float4*)(h + (size_t)sB * C1 + ch);
    float wtA = __expf((lo_head ? eA.x : eA.y) - Msel) * isel;
    float wtB = __expf((lo_head ? eB.x : eB.y) - Msel) * isel;
    accA.x += wtA * ha.x; accA.y += wtA * ha.y; accA.z += wtA * ha.z; accA.w += wtA * ha.w;
    accB.x += wtB * hb.x; accB.y += wtB * hb.y; accB.z += wtB * hb.z; accB.w += wtB * hb.w;
  }
  if (j < deg) {
    int i0 = lo + j;
    float2 eA = eb[i0];
    int sA = ssort[i0];
    float4 ha = *(const float4*)(h + (size_t)sA * C1 + ch);
    float wtA = __expf((lo_head ? eA.x : eA.y) - Msel) * isel;
    accA.x += wtA * ha.x; accA.y += wtA * ha.y; accA.z += wtA * ha.z; accA.w += wtA * ha.w;
  }
  accA.x += accB.x; accA.y += accB.y; accA.z += accB.z; accA.w += accB.w;
  *(float4*)&slab[w][ch] = accA;
  __syncthreads();
  float v = slab[0][tid] + slab[1][tid] + slab[2][tid] + slab[3][tid] + b1[tid];
  ho[(size_t)n * C1 + tid] = v > 0.f ? v : __expf(v) - 1.0f;   // ELU
}

// ---------------- layer 2: wave-per-node, fused softmax+gather+normalize ----------------
__global__ __launch_bounds__(256) void agg2_kernel(const float* __restrict__ h,
    const float* __restrict__ eb, const int* __restrict__ ssort,
    const float* __restrict__ b2, const int* __restrict__ rowp,
    float* __restrict__ emb, float* __restrict__ dnrm) {
  int tid = threadIdx.x;
  int w = tid >> 6, l = tid & 63;
  int n = (blockIdx.x << 2) + w;
  int lo = rowp[n], hi = rowp[n + 1];
  float m = -1e30f, s = 0.f;
  for (int i = lo + l; i < hi; i += 64) {
    float e = eb[i];
    if (e > m) { s = s * __expf(m - e) + 1.f; m = e; }
    else s += __expf(e - m);
  }
#pragma unroll
  for (int off = 32; off > 0; off >>= 1) {
    float om = __shfl_xor(m, off, 64), os = __shfl_xor(s, off, 64);
    float nm = fmaxf(m, om);
    s = s * __expf(m - nm) + os * __expf(om - nm); m = nm;
  }
  float inv = 1.f / (s + 1e-16f);
  int g = l >> 4, lg = l & 15, ch = lg << 2;
  int deg = hi - lo;
  float4 accA = {0.f, 0.f, 0.f, 0.f}, accB = {0.f, 0.f, 0.f, 0.f};
  int j = g;
  for (; j + 4 < deg; j += 8) {
    int i0 = lo + j, i1 = lo + j + 4;
    float eA = eb[i0], eB = eb[i1];
    int sA = ssort[i0], sB = ssort[i1];
    float4 ha = *(const float4*)(h + (size_t)sA * C2 + ch);
    float4 hb = *(const float4*)(h + (size_t)sB * C2 + ch);
    float wtA = __expf(eA - m) * inv;
    float wtB = __expf(eB - m) * inv;
    accA.x += wtA * ha.x; accA.y += wtA * ha.y; accA.z += wtA * ha.z; accA.w += wtA * ha.w;
    accB.x += wtB * hb.x; accB.y += wtB * hb.y; accB.z += wtB * hb.z; accB.w += wtB * hb.w;
  }
  if (j < deg) {
    int i0 = lo + j;
    float eA = eb[i0];
    int sA = ssort[i0];
    float4 ha = *(const float4*)(h + (size_t)sA * C2 + ch);
    float wtA = __expf(eA - m) * inv;
    accA.x += wtA * ha.x; accA.y += wtA * ha.y; accA.z += wtA * ha.z; accA.w += wtA * ha.w;
  }
  accA.x += accB.x; accA.y += accB.y; accA.z += accB.z; accA.w += accB.w;
#pragma unroll
  for (int off = 16; off <= 32; off <<= 1) {
    accA.x += __shfl_xor(accA.x, off, 64);
    accA.y += __shfl_xor(accA.y, off, 64);
    accA.z += __shfl_xor(accA.z, off, 64);
    accA.w += __shfl_xor(accA.w, off, 64);
  }
  float4 bv = *(const float4*)(b2 + ch);
  float e0 = accA.x + bv.x + 1e-6f;
  float e1 = accA.y + bv.y + 1e-6f;
  float e2 = accA.z + bv.z + 1e-6f;
  float e3 = accA.w + bv.w + 1e-6f;
  float dot = e0 * e0 + e1 * e1 + e2 * e2 + e3 * e3;
#pragma unroll
  for (int off = 1; off < 16; off <<= 1) dot += __shfl_xor(dot, off, 64);
  float invn = 1.f / sqrtf(dot);
  if (g == 0) {
    *(float4*)(emb + (size_t)n * C2 + ch) = make_float4(e0, e1, e2, e3);
    *(float4*)(dnrm + (size_t)n * C2 + ch) =
        make_float4(e0 * invn, e1 * invn, e2 * invn, e3 * invn);
  }
}

// ---------------- cooperative clustering: all iterations in one kernel ----------------
__global__ __launch_bounds__(256) void coop_cluster(
    const float* __restrict__ dnp, const float* __restrict__ mu0,
    float* __restrict__ mu, float* __restrict__ pcm, float* __restrict__ pcr,
    float* __restrict__ out_mu, float* __restrict__ out_r, float* __restrict__ out_d,
    const int* __restrict__ niter) {
  cg::grid_group gg = cg::this_grid();
  __shared__ float mu_s[KC * 65];
  __shared__ __align__(16) float d_s[CHB * 68];
  __shared__ float r_s[CHB * KC];
  __shared__ float part[4][64];
  __shared__ float redc[4];
  int tid = threadIdx.x, blk = blockIdx.x;
  int w = tid >> 6, l = tid & 63;
  const bool has2 = l < (KC - 64);
  int l2 = has2 ? 64 + l : l;
  for (int idx = tid; idx < CHB * 64; idx += 256)
    d_s[(idx >> 6) * 68 + (idx & 63)] = dnp[(size_t)blk * (CHB * 64) + idx];
  for (int idx = tid; idx < KC * 64; idx += 256)
    mu_s[(idx >> 6) * 65 + (idx & 63)] = mu0[idx];
  __syncthreads();
  int NI = niter[0];
  for (int it = 0; it <= NI; ++it) {
    // ---- assign: r_s = softmax(TEMP * d @ mu^T) for my 80 nodes
    for (int g = 0; g < 5; g++) {
      int nl0 = w * 20 + g * 4;
      float z1[4] = {0.f, 0.f, 0.f, 0.f}, z2[4] = {0.f, 0.f, 0.f, 0.f};
#pragma unroll 8
      for (int d = 0; d < 64; d++) {
        float m1v = mu_s[l * 65 + d];
        float m2v = mu_s[l2 * 65 + d];
#pragma unroll
        for (int nb = 0; nb < 4; nb++) {
          float dv = d_s[(nl0 + nb) * 68 + d];
          z1[nb] += m1v * dv;
          z2[nb] += m2v * dv;
        }
      }
#pragma unroll
      for (int nb = 0; nb < 4; nb++) {
        float g1 = TEMP * z1[nb];
        float g2 = has2 ? TEMP * z2[nb] : -1e30f;
        float m = wredMax(fmaxf(g1, g2));
        float e1 = expf(g1 - m);
        float e2 = has2 ? expf(g2 - m) : 0.f;
        float inv = 1.0f / wredSum(e1 + e2);
        int nl = nl0 + nb;
        r_s[nl * KC + l] = e1 * inv;
        if (has2) r_s[nl * KC + 64 + l] = e2 * inv;
      }
    }
    __syncthreads();
    // ---- partial cluster mean
    {
      int tx = tid & 15, ky = tid >> 4;
      float acc[7][4] = {};
      float accr[7] = {};
      for (int j = 0; j < CHB; j++) {
        float4 dv = *(const float4*)&d_s[j * 68 + (tx << 2)];
#pragma unroll
        for (int jj = 0; jj < 7; jj++) {
          int kk = ky + (jj << 4);
          if (kk < KC) {
            float rv = r_s[j * KC + kk];
            acc[jj][0] += rv * dv.x; acc[jj][1] += rv * dv.y;
            acc[jj][2] += rv * dv.z; acc[jj][3] += rv * dv.w;
            if (tx == 0) accr[jj] += rv;
          }
        }
      }
#pragma unroll
      for (int jj = 0; jj < 7; jj++) {
        int kk = ky + (jj << 4);
        if (kk < KC) {
          float* p = pcm + (size_t)blk * 6400 + kk * 64 + (tx << 2);
          p[0] = acc[jj][0]; p[1] = acc[jj][1]; p[2] = acc[jj][2]; p[3] = acc[jj][3];
          if (tx == 0) pcr[blk * KC + kk] = accr[jj];
        }
      }
    }
    gg.sync();
    // ---- mu update: block k (k<100) reduces over 250 partials
    if (blk < KC) {
      int k = blk;
      int d = tid & 63, bg = tid >> 6;
      float s = 0.f;
      for (int b = bg; b < NPART; b += 4)
        s += pcm[(size_t)b * 6400 + k * 64 + d];
      part[bg][d] = s;
      float c = (tid < NPART) ? pcr[tid * KC + k] : 0.f;
      c = wredSum(c);
      if (l == 0) redc[w] = c;
      __syncthreads();
      if (tid < 64) {
        float cr = redc[0] + redc[1] + redc[2] + redc[3];
        mu[k * 64 + tid] = (part[0][tid] + part[1][tid] + part[2][tid] + part[3][tid]) / cr;
      }
    }
    gg.sync();
    // ---- reload mu
    for (int idx = tid; idx < KC * 64; idx += 256)
      mu_s[(idx >> 6) * 65 + (idx & 63)] = mu[idx];
    __syncthreads();
  }
  // ---- final assign: write r and dist from final mu
  for (int g = 0; g < 5; g++) {
    int nl0 = w * 20 + g * 4;
    float z1[4] = {0.f, 0.f, 0.f, 0.f}, z2[4] = {0.f, 0.f, 0.f, 0.f};
#pragma unroll 8
    for (int d = 0; d < 64; d++) {
      float m1v = mu_s[l * 65 + d];
      float m2v = mu_s[l2 * 65 + d];
#pragma unroll
      for (int nb = 0; nb < 4; nb++) {
        float dv = d_s[(nl0 + nb) * 68 + d];
        z1[nb] += m1v * dv;
        z2[nb] += m2v * dv;
      }
    }
#pragma unroll
    for (int nb = 0; nb < 4; nb++) {
      float g1 = TEMP * z1[nb];
      float g2 = has2 ? TEMP * z2[nb] : -1e30f;
      float m = wredMax(fmaxf(g1, g2));
      float e1 = expf(g1 - m);
      float e2 = has2 ? expf(g2 - m) : 0.f;
      float inv = 1.0f / wredSum(e1 + e2);
      size_t n = (size_t)blk * CHB + nl0 + nb;
      out_r[n * KC + l] = e1 * inv;
      if (has2) out_r[n * KC + 64 + l] = e2 * inv;
      out_d[n * KC + l] = z1[nb];
      if (has2) out_d[n * KC + 64 + l] = z2[nb];
    }
  }
  if (blk == 0) {
    for (int idx = tid; idx < KC * 64; idx += 256)
      out_mu[idx] = mu_s[(idx >> 6) * 65 + (idx & 63)];
  }
}

extern "C" void kernel_launch(void* const* d_in, const int* in_sizes, int n_in,
                              void* d_out, int out_size, void* d_ws, size_t ws_size,
                              hipStream_t stream) {
  const float* x    = (const float*)d_in[0];
  const float* W1   = (const float*)d_in[1];
  const float* asr1 = (const float*)d_in[2];
  const float* ads1 = (const float*)d_in[3];
  const float* b1   = (const float*)d_in[4];
  const float* W2   = (const float*)d_in[5];
  const float* asr2 = (const float*)d_in[6];
  const float* ads2 = (const float*)d_in[7];
  const float* b2   = (const float*)d_in[8];
  const float* mu0  = (const float*)d_in[9];
  const int*   ei   = (const int*)d_in[10];
  const int*   nit  = (const int*)d_in[11];

  float* f = (float*)d_ws;
  float* h1   = f;  f += (size_t)Nn * C1;
  float* h1o  = f;  f += (size_t)Nn * C1;
  float* as1  = f;  f += Nn * 2;
  float* ad1  = f;  f += Nn * 2;
  float* h2   = f;  f += (size_t)Nn * C2;
  float* as2  = f;  f += Nn;
  float* ad2  = f;  f += Nn;
  float* dn   = f;  f += (size_t)Nn * C2;
  float* pcm  = f;  f += (size_t)NPART * 6400;
  float* pcr  = f;  f += NPART * KC;
  float* mu   = f;  f += KC * C2;
  float2* ebA = (float2*)f; f += (size_t)ETOT * 2;
  float* ebB  = (float*)ebA;            // layer-2 logits reuse layer-1 buffer
  int* ip = (int*)f;
  int* deg   = ip;  ip += Nn;
  int* rowp  = ip;  ip += Nn + 1;
  int* curs  = ip;  ip += Nn;
  int* ssort = ip;  ip += ETOT;
  int* dsort = ip;  ip += ETOT;

  float* out_mu = (float*)d_out;
  float* out_r  = out_mu + KC * C2;
  float* out_e  = out_r + (size_t)Nn * KC;
  float* out_d  = out_e + (size_t)Nn * C2;

  hipMemsetAsync(deg, 0, Nn * sizeof(int), stream);
  hist_kernel<<<(ETOT + 255) / 256, 256, 0, stream>>>(ei, deg);
  scan2_kernel<<<1, 1024, 0, stream>>>(deg, rowp, curs);
  scatter_kernel<<<(ETOT + 255) / 256, 256, 0, stream>>>(ei, curs, ssort, dsort);

  gemm1_mfma<<<dim3(157, 2), 256, 0, stream>>>(x, W1, h1);
  alpha1_kernel<<<5000, 256, 0, stream>>>(h1, asr1, ads1, as1, ad1);
  edge_e1<<<(ETOT + 255) / 256, 256, 0, stream>>>(ssort, dsort, as1, ad1, ebA);
  agg1_kernel<<<Nn, 256, 0, stream>>>(h1, ebA, ssort, b1, rowp, h1o);

  gemm_nt<<<dim3(313, 1), 256, 0, stream>>>(h1o, W2, h2, Nn, C2, C1);
  alpha2_kernel<<<5000, 256, 0, stream>>>(h2, asr2, ads2, as2, ad2);
  edge_e2<<<(ETOT + 255) / 256, 256, 0, stream>>>(ssort, dsort, as2, ad2, ebB);
  agg2_kernel<<<5000, 256, 0, stream>>>(h2, ebB, ssort, b2, rowp, out_e, dn);

  void* cargs[] = {(void*)&dn, (void*)&mu0, (void*)&mu, (void*)&pcm, (void*)&pcr,
                   (void*)&out_mu, (void*)&out_r, (void*)&out_d, (void*)&nit};
  hipLaunchCooperativeKernel((void*)coop_cluster, dim3(NPART), dim3(256), cargs, 0, stream);
}

// Round 6
// 1129.203 us; speedup vs baseline: 1.4805x; 1.4805x over previous
//
#include <hip/hip_runtime.h>
#include <hip/hip_bf16.h>
#include <math.h>

#define Nn 20000
#define Ee 640000
#define ETOT 660000   // Ee + Nn self loops
#define NF 512
#define C1 256        // HEADS*NHID
#define C2 64         // NOUT
#define KC 100
#define TEMP 5.0f
#define NSLOPE 0.2f
#define NPB 500       // clustering blocks
#define CHB 40        // nodes per clustering block (500*40 = 20000)

typedef __attribute__((ext_vector_type(8))) short bf16x8;
typedef __attribute__((ext_vector_type(4))) float f32x4;

__device__ __forceinline__ float wredSum(float v) {
#pragma unroll
  for (int off = 32; off > 0; off >>= 1) v += __shfl_xor(v, off, 64);
  return v;
}
__device__ __forceinline__ ushort f2bf(float f) {
  __hip_bfloat16 b = __float2bfloat16(f);
  return *(ushort*)&b;
}
__device__ __forceinline__ float bf2f(ushort u) {
  __hip_bfloat16 b = *(__hip_bfloat16*)&u;
  return __bfloat162float(b);
}

// ---------------- CSR build ----------------
__global__ void hist_kernel(const int* __restrict__ ei, int* __restrict__ deg) {
  int e = blockIdx.x * 256 + threadIdx.x;
  if (e >= ETOT) return;
  int dst = e < Ee ? ei[Ee + e] : e - Ee;
  atomicAdd(&deg[dst], 1);
}

__global__ __launch_bounds__(1024) void scan2_kernel(const int* __restrict__ deg,
    int* __restrict__ rowp, int* __restrict__ curs) {
  __shared__ int wsum[16];
  __shared__ int wpre[16];
  int t = threadIdx.x;
  int lane = t & 63, w = t >> 6;
  int loc[20];
  int tot = 0;
  int base = t * 20;
  if (t < 1000) {
#pragma unroll
    for (int i = 0; i < 20; i++) { tot += deg[base + i]; loc[i] = tot; }
  }
  int s = tot;
#pragma unroll
  for (int off = 1; off < 64; off <<= 1) {
    int u = __shfl_up(s, off, 64);
    if (lane >= off) s += u;
  }
  if (lane == 63) wsum[w] = s;
  __syncthreads();
  if (t == 0) {
    int c = 0;
#pragma unroll
    for (int i = 0; i < 16; i++) { c += wsum[i]; wpre[i] = c; }
    rowp[0] = 0;
  }
  __syncthreads();
  int p = (w > 0 ? wpre[w - 1] : 0) + s - tot;
  if (t < 1000) {
    int prev = 0;
#pragma unroll
    for (int i = 0; i < 20; i++) {
      rowp[base + i + 1] = p + loc[i];
      curs[base + i] = p + prev;
      prev = loc[i];
    }
  }
}

__global__ void scatter_kernel(const int* __restrict__ ei, int* __restrict__ curs,
                               int* __restrict__ ssort, int* __restrict__ dsort) {
  int e = blockIdx.x * 256 + threadIdx.x;
  if (e >= ETOT) return;
  int src = e < Ee ? ei[e] : e - Ee;
  int dst = e < Ee ? ei[Ee + e] : e - Ee;
  int pos = atomicAdd(&curs[dst], 1);
  ssort[pos] = src;
  dsort[pos] = dst;
}

// ---------------- per-edge logits (LeakyReLU'd), CSR order ----------------
__global__ __launch_bounds__(256) void edge_e1(const int* __restrict__ ssort,
    const int* __restrict__ dsort, const float* __restrict__ asn,
    const float* __restrict__ adn, float2* __restrict__ eb) {
  int i = blockIdx.x * 256 + threadIdx.x;
  if (i >= ETOT) return;
  int s = ssort[i], d = dsort[i];
  float2 a = ((const float2*)asn)[s];
  float2 b = ((const float2*)adn)[d];
  float e0 = a.x + b.x, e1 = a.y + b.y;
  e0 = e0 > 0.f ? e0 : NSLOPE * e0;
  e1 = e1 > 0.f ? e1 : NSLOPE * e1;
  eb[i] = make_float2(e0, e1);
}

__global__ __launch_bounds__(256) void edge_e2(const int* __restrict__ ssort,
    const int* __restrict__ dsort, const float* __restrict__ asn,
    const float* __restrict__ adn, float* __restrict__ eb) {
  int i = blockIdx.x * 256 + threadIdx.x;
  if (i >= ETOT) return;
  float e = asn[ssort[i]] + adn[dsort[i]];
  eb[i] = e > 0.f ? e : NSLOPE * e;
}

// ---------------- GEMM1 via split-bf16 MFMA (3-pass Markidis) ----------------
__global__ __launch_bounds__(256) void gemm1_mfma(const float* __restrict__ A,
    const float* __restrict__ B, float* __restrict__ C) {
  __shared__ ushort Ah[128 * 40], Al[128 * 40], Bh[128 * 40], Bl[128 * 40];
  int tid = threadIdx.x;
  int bm = blockIdx.x << 7, bn = blockIdx.y << 7;
  int w = tid >> 6, lane = tid & 63;
  int wm = (w >> 1) << 6, wn = (w & 1) << 6;
  int fr = lane & 15, ko = (lane >> 4) << 3;
  f32x4 acc[4][4] = {};
  for (int k0 = 0; k0 < 512; k0 += 32) {
    __syncthreads();
#pragma unroll
    for (int cc = 0; cc < 4; cc++) {
      int c = tid + (cc << 8);
      int row = c >> 3, q = c & 7;
      int off = row * 40 + (q << 2);
      int gr = bm + row;
      float4 va = (gr < Nn) ? *(const float4*)(A + (size_t)gr * NF + k0 + (q << 2))
                            : make_float4(0.f, 0.f, 0.f, 0.f);
      float4 vb = *(const float4*)(B + (size_t)(bn + row) * NF + k0 + (q << 2));
      ushort h0 = f2bf(va.x), h1 = f2bf(va.y), h2 = f2bf(va.z), h3 = f2bf(va.w);
      *(ushort4*)&Ah[off] = make_ushort4(h0, h1, h2, h3);
      *(ushort4*)&Al[off] = make_ushort4(
          f2bf(va.x - bf2f(h0)), f2bf(va.y - bf2f(h1)),
          f2bf(va.z - bf2f(h2)), f2bf(va.w - bf2f(h3)));
      ushort g0 = f2bf(vb.x), g1 = f2bf(vb.y), g2 = f2bf(vb.z), g3 = f2bf(vb.w);
      *(ushort4*)&Bh[off] = make_ushort4(g0, g1, g2, g3);
      *(ushort4*)&Bl[off] = make_ushort4(
          f2bf(vb.x - bf2f(g0)), f2bf(vb.y - bf2f(g1)),
          f2bf(vb.z - bf2f(g2)), f2bf(vb.w - bf2f(g3)));
    }
    __syncthreads();
    bf16x8 aH[4], bH[4], t[4];
#pragma unroll
    for (int mf = 0; mf < 4; mf++)
      aH[mf] = *(const bf16x8*)&Ah[(wm + (mf << 4) + fr) * 40 + ko];
#pragma unroll
    for (int nf = 0; nf < 4; nf++)
      bH[nf] = *(const bf16x8*)&Bh[(wn + (nf << 4) + fr) * 40 + ko];
#pragma unroll
    for (int mf = 0; mf < 4; mf++)
#pragma unroll
      for (int nf = 0; nf < 4; nf++)
        acc[mf][nf] = __builtin_amdgcn_mfma_f32_16x16x32_bf16(aH[mf], bH[nf], acc[mf][nf], 0, 0, 0);
#pragma unroll
    for (int nf = 0; nf < 4; nf++)
      t[nf] = *(const bf16x8*)&Bl[(wn + (nf << 4) + fr) * 40 + ko];
#pragma unroll
    for (int mf = 0; mf < 4; mf++)
#pragma unroll
      for (int nf = 0; nf < 4; nf++)
        acc[mf][nf] = __builtin_amdgcn_mfma_f32_16x16x32_bf16(aH[mf], t[nf], acc[mf][nf], 0, 0, 0);
#pragma unroll
    for (int mf = 0; mf < 4; mf++)
      t[mf] = *(const bf16x8*)&Al[(wm + (mf << 4) + fr) * 40 + ko];
#pragma unroll
    for (int mf = 0; mf < 4; mf++)
#pragma unroll
      for (int nf = 0; nf < 4; nf++)
        acc[mf][nf] = __builtin_amdgcn_mfma_f32_16x16x32_bf16(t[mf], bH[nf], acc[mf][nf], 0, 0, 0);
  }
  int cr = (lane >> 4) << 2, cc2 = lane & 15;
#pragma unroll
  for (int mf = 0; mf < 4; mf++) {
#pragma unroll
    for (int r = 0; r < 4; r++) {
      int row = bm + wm + (mf << 4) + cr + r;
      if (row < Nn) {
#pragma unroll
        for (int nf = 0; nf < 4; nf++)
          C[(size_t)row * C1 + bn + wn + (nf << 4) + cc2] = acc[mf][nf][r];
      }
    }
  }
}

// ---------------- f32 GEMM 64x64 (GEMM2, N=64) ----------------
__global__ __launch_bounds__(256) void gemm_nt(const float* __restrict__ A,
    const float* __restrict__ B, float* __restrict__ C, int M, int N, int K) {
  __shared__ __align__(16) float As[16][68];
  __shared__ __align__(16) float Bs[16][68];
  int tid = threadIdx.x;
  int bm = blockIdx.x << 6, bn = blockIdx.y << 6;
  int lr = tid >> 2;
  int lc = (tid & 3) << 2;
  int tx = tid & 15, ty = tid >> 4;
  float acc[4][4] = {};
  for (int k0 = 0; k0 < K; k0 += 16) {
    int am = bm + lr;
    float4 av = make_float4(0.f, 0.f, 0.f, 0.f);
    if (am < M) av = *(const float4*)(A + (size_t)am * K + k0 + lc);
    float4 bv = *(const float4*)(B + (size_t)(bn + lr) * K + k0 + lc);
    __syncthreads();
    As[lc + 0][lr] = av.x; As[lc + 1][lr] = av.y; As[lc + 2][lr] = av.z; As[lc + 3][lr] = av.w;
    Bs[lc + 0][lr] = bv.x; Bs[lc + 1][lr] = bv.y; Bs[lc + 2][lr] = bv.z; Bs[lc + 3][lr] = bv.w;
    __syncthreads();
#pragma unroll
    for (int k = 0; k < 16; k++) {
      float4 a = *(const float4*)&As[k][ty << 2];
      float4 b = *(const float4*)&Bs[k][tx << 2];
      float aa[4] = {a.x, a.y, a.z, a.w};
      float bb[4] = {b.x, b.y, b.z, b.w};
#pragma unroll
      for (int i = 0; i < 4; i++)
#pragma unroll
        for (int j = 0; j < 4; j++) acc[i][j] += aa[i] * bb[j];
    }
  }
#pragma unroll
  for (int i = 0; i < 4; i++) {
    int row = bm + (ty << 2) + i;
    if (row < M) {
#pragma unroll
      for (int j = 0; j < 4; j++)
        C[(size_t)row * N + bn + (tx << 2) + j] = acc[i][j];
    }
  }
}

// ---------------- per-node attention scalars ----------------
__global__ __launch_bounds__(256) void alpha1_kernel(const float* __restrict__ h,
    const float* __restrict__ a_src, const float* __restrict__ a_dst,
    float* __restrict__ asn, float* __restrict__ adn) {
  int l = threadIdx.x & 63;
  int n = (blockIdx.x << 2) + (threadIdx.x >> 6);
  if (n >= Nn) return;
  const float* hr = h + (size_t)n * C1;
  float h0 = hr[l], h1v = hr[64 + l], h2v = hr[128 + l], h3v = hr[192 + l];
  float ps0 = h0 * a_src[l] + h1v * a_src[64 + l];
  float pd0 = h0 * a_dst[l] + h1v * a_dst[64 + l];
  float ps1 = h2v * a_src[128 + l] + h3v * a_src[192 + l];
  float pd1 = h2v * a_dst[128 + l] + h3v * a_dst[192 + l];
  ps0 = wredSum(ps0); pd0 = wredSum(pd0); ps1 = wredSum(ps1); pd1 = wredSum(pd1);
  if (l == 0) {
    asn[2 * n] = ps0; asn[2 * n + 1] = ps1;
    adn[2 * n] = pd0; adn[2 * n + 1] = pd1;
  }
}

__global__ __launch_bounds__(256) void alpha2_kernel(const float* __restrict__ h,
    const float* __restrict__ a_src, const float* __restrict__ a_dst,
    float* __restrict__ asn, float* __restrict__ adn) {
  int l = threadIdx.x & 63;
  int n = (blockIdx.x << 2) + (threadIdx.x >> 6);
  if (n >= Nn) return;
  float v = h[(size_t)n * C2 + l];
  float ps = wredSum(v * a_src[l]);
  float pd = wredSum(v * a_dst[l]);
  if (l == 0) { asn[n] = ps; adn[n] = pd; }
}

// ---------------- layer 1: online segment softmax + float4 gather + ELU ----------------
__global__ __launch_bounds__(256) void agg1_kernel(const float* __restrict__ h,
    const float2* __restrict__ eb, const int* __restrict__ ssort,
    const float* __restrict__ b1, const int* __restrict__ rowp,
    float* __restrict__ ho) {
  __shared__ float redm[8], reds[8];
  __shared__ __align__(16) float slab[4][256];
  int n = blockIdx.x, tid = threadIdx.x;
  int w = tid >> 6, l = tid & 63;
  int lo = rowp[n], hi = rowp[n + 1];
  float m0 = -1e30f, s0 = 0.f, m1 = -1e30f, s1 = 0.f;
  for (int i = lo + tid; i < hi; i += 256) {
    float2 e = eb[i];
    if (e.x > m0) { s0 = s0 * __expf(m0 - e.x) + 1.f; m0 = e.x; }
    else s0 += __expf(e.x - m0);
    if (e.y > m1) { s1 = s1 * __expf(m1 - e.y) + 1.f; m1 = e.y; }
    else s1 += __expf(e.y - m1);
  }
#pragma unroll
  for (int off = 32; off > 0; off >>= 1) {
    float om = __shfl_xor(m0, off, 64), os = __shfl_xor(s0, off, 64);
    float nm = fmaxf(m0, om);
    s0 = s0 * __expf(m0 - nm) + os * __expf(om - nm); m0 = nm;
    om = __shfl_xor(m1, off, 64); os = __shfl_xor(s1, off, 64);
    nm = fmaxf(m1, om);
    s1 = s1 * __expf(m1 - nm) + os * __expf(om - nm); m1 = nm;
  }
  if (l == 0) { redm[w] = m0; reds[w] = s0; redm[4 + w] = m1; reds[4 + w] = s1; }
  __syncthreads();
  float M0 = fmaxf(fmaxf(redm[0], redm[1]), fmaxf(redm[2], redm[3]));
  float M1 = fmaxf(fmaxf(redm[4], redm[5]), fmaxf(redm[6], redm[7]));
  float S0 = reds[0] * __expf(redm[0] - M0) + reds[1] * __expf(redm[1] - M0)
           + reds[2] * __expf(redm[2] - M0) + reds[3] * __expf(redm[3] - M0);
  float S1 = reds[4] * __expf(redm[4] - M1) + reds[5] * __expf(redm[5] - M1)
           + reds[6] * __expf(redm[6] - M1) + reds[7] * __expf(redm[7] - M1);
  float inv0 = 1.f / (S0 + 1e-16f), inv1 = 1.f / (S1 + 1e-16f);
  const bool lo_head = (l < 32);
  float Msel = lo_head ? M0 : M1;
  float isel = lo_head ? inv0 : inv1;
  int ch = l << 2;
  int deg = hi - lo;
  float4 accA = {0.f, 0.f, 0.f, 0.f}, accB = {0.f, 0.f, 0.f, 0.f};
  int j = w;
  for (; j + 4 < deg; j += 8) {
    int i0 = lo + j, i1 = lo + j + 4;
    float2 eA = eb[i0];
    float2 eB = eb[i1];
    int sA = ssort[i0], sB = ssort[i1];
    float4 ha = *(const float4*)(h + (size_t)sA * C1 + ch);
    float4 hb = *(const float4*)(h + (size_t)sB * C1 + ch);
    float wtA = __expf((lo_head ? eA.x : eA.y) - Msel) * isel;
    float wtB = __expf((lo_head ? eB.x : eB.y) - Msel) * isel;
    accA.x += wtA * ha.x; accA.y += wtA * ha.y; accA.z += wtA * ha.z; accA.w += wtA * ha.w;
    accB.x += wtB * hb.x; accB.y += wtB * hb.y; accB.z += wtB * hb.z; accB.w += wtB * hb.w;
  }
  if (j < deg) {
    int i0 = lo + j;
    float2 eA = eb[i0];
    int sA = ssort[i0];
    float4 ha = *(const float4*)(h + (size_t)sA * C1 + ch);
    float wtA = __expf((lo_head ? eA.x : eA.y) - Msel) * isel;
    accA.x += wtA * ha.x; accA.y += wtA * ha.y; accA.z += wtA * ha.z; accA.w += wtA * ha.w;
  }
  accA.x += accB.x; accA.y += accB.y; accA.z += accB.z; accA.w += accB.w;
  *(float4*)&slab[w][ch] = accA;
  __syncthreads();
  float v = slab[0][tid] + slab[1][tid] + slab[2][tid] + slab[3][tid] + b1[tid];
  ho[(size_t)n * C1 + tid] = v > 0.f ? v : __expf(v) - 1.0f;   // ELU
}

// ---------------- layer 2: wave-per-node, fused softmax+gather+normalize ----------------
__global__ __launch_bounds__(256) void agg2_kernel(const float* __restrict__ h,
    const float* __restrict__ eb, const int* __restrict__ ssort,
    const float* __restrict__ b2, const int* __restrict__ rowp,
    float* __restrict__ emb, float* __restrict__ dnrm) {
  int tid = threadIdx.x;
  int w = tid >> 6, l = tid & 63;
  int n = (blockIdx.x << 2) + w;
  int lo = rowp[n], hi = rowp[n + 1];
  float m = -1e30f, s = 0.f;
  for (int i = lo + l; i < hi; i += 64) {
    float e = eb[i];
    if (e > m) { s = s * __expf(m - e) + 1.f; m = e; }
    else s += __expf(e - m);
  }
#pragma unroll
  for (int off = 32; off > 0; off >>= 1) {
    float om = __shfl_xor(m, off, 64), os = __shfl_xor(s, off, 64);
    float nm = fmaxf(m, om);
    s = s * __expf(m - nm) + os * __expf(om - nm); m = nm;
  }
  float inv = 1.f / (s + 1e-16f);
  int g = l >> 4, lg = l & 15, ch = lg << 2;
  int deg = hi - lo;
  float4 accA = {0.f, 0.f, 0.f, 0.f}, accB = {0.f, 0.f, 0.f, 0.f};
  int j = g;
  for (; j + 4 < deg; j += 8) {
    int i0 = lo + j, i1 = lo + j + 4;
    float eA = eb[i0], eB = eb[i1];
    int sA = ssort[i0], sB = ssort[i1];
    float4 ha = *(const float4*)(h + (size_t)sA * C2 + ch);
    float4 hb = *(const float4*)(h + (size_t)sB * C2 + ch);
    float wtA = __expf(eA - m) * inv;
    float wtB = __expf(eB - m) * inv;
    accA.x += wtA * ha.x; accA.y += wtA * ha.y; accA.z += wtA * ha.z; accA.w += wtA * ha.w;
    accB.x += wtB * hb.x; accB.y += wtB * hb.y; accB.z += wtB * hb.z; accB.w += wtB * hb.w;
  }
  if (j < deg) {
    int i0 = lo + j;
    float eA = eb[i0];
    int sA = ssort[i0];
    float4 ha = *(const float4*)(h + (size_t)sA * C2 + ch);
    float wtA = __expf(eA - m) * inv;
    accA.x += wtA * ha.x; accA.y += wtA * ha.y; accA.z += wtA * ha.z; accA.w += wtA * ha.w;
  }
  accA.x += accB.x; accA.y += accB.y; accA.z += accB.z; accA.w += accB.w;
#pragma unroll
  for (int off = 16; off <= 32; off <<= 1) {
    accA.x += __shfl_xor(accA.x, off, 64);
    accA.y += __shfl_xor(accA.y, off, 64);
    accA.z += __shfl_xor(accA.z, off, 64);
    accA.w += __shfl_xor(accA.w, off, 64);
  }
  float4 bv = *(const float4*)(b2 + ch);
  float e0 = accA.x + bv.x + 1e-6f;
  float e1 = accA.y + bv.y + 1e-6f;
  float e2 = accA.z + bv.z + 1e-6f;
  float e3 = accA.w + bv.w + 1e-6f;
  float dot = e0 * e0 + e1 * e1 + e2 * e2 + e3 * e3;
#pragma unroll
  for (int off = 1; off < 16; off <<= 1) dot += __shfl_xor(dot, off, 64);
  float invn = 1.f / sqrtf(dot);
  if (g == 0) {
    *(float4*)(emb + (size_t)n * C2 + ch) = make_float4(e0, e1, e2, e3);
    *(float4*)(dnrm + (size_t)n * C2 + ch) =
        make_float4(e0 * invn, e1 * invn, e2 * invn, e3 * invn);
  }
}

// ---------------- clustering: per-iteration fused assign (+partial cmean) ----------------
// 500 blocks x 40 nodes; LDS 52.9 KB -> 3 blocks/CU schedulable. No max-sub
// in softmax (|5z| <= ~5, exp safe in f32). MODE 1: final assign -> r, dist.
template <int MODE>
__global__ __launch_bounds__(256) void fused_ac(
    const float* __restrict__ dnp, const float* __restrict__ mu_init,
    const float* __restrict__ mu, float* __restrict__ pcm, float* __restrict__ pcr,
    float* __restrict__ rout, float* __restrict__ distout,
    int it, const int* __restrict__ niter) {
  if (MODE == 0) { if (it > niter[0]) return; }
  __shared__ float mu_s[KC * 65];
  __shared__ __align__(16) float d_s[CHB * 68];
  __shared__ float r_s[CHB * KC];
  int tid = threadIdx.x, blk = blockIdx.x;
  const float* msrc = (MODE == 0 && it == 0) ? mu_init : mu;
  for (int idx = tid; idx < KC * 64; idx += 256)
    mu_s[(idx >> 6) * 65 + (idx & 63)] = msrc[idx];
  for (int idx = tid; idx < CHB * 64; idx += 256)
    d_s[(idx >> 6) * 68 + (idx & 63)] = dnp[(size_t)blk * (CHB * 64) + idx];
  __syncthreads();
  int w = tid >> 6, l = tid & 63;
  const bool has2 = l < (KC - 64);
  int l2 = has2 ? 64 + l : l;
  for (int g = 0; g < 5; g++) {
    int nl0 = w * 10 + g * 2;
    float z1[2] = {0.f, 0.f}, z2[2] = {0.f, 0.f};
#pragma unroll 16
    for (int d = 0; d < 64; d++) {
      float m1v = mu_s[l * 65 + d];
      float m2v = mu_s[l2 * 65 + d];
#pragma unroll
      for (int nb = 0; nb < 2; nb++) {
        float dv = d_s[(nl0 + nb) * 68 + d];
        z1[nb] += m1v * dv;
        z2[nb] += m2v * dv;
      }
    }
#pragma unroll
    for (int nb = 0; nb < 2; nb++) {
      float e1 = __expf(TEMP * z1[nb]);
      float e2 = has2 ? __expf(TEMP * z2[nb]) : 0.f;
      float inv = 1.0f / wredSum(e1 + e2);
      int nl = nl0 + nb;
      if (MODE == 0) {
        r_s[nl * KC + l] = e1 * inv;
        if (has2) r_s[nl * KC + 64 + l] = e2 * inv;
      } else {
        size_t n = (size_t)blk * CHB + nl;
        rout[n * KC + l] = e1 * inv;
        if (has2) rout[n * KC + 64 + l] = e2 * inv;
        distout[n * KC + l] = z1[nb];
        if (has2) distout[n * KC + 64 + l] = z2[nb];
      }
    }
  }
  if (MODE == 0) {
    __syncthreads();
    int tx = tid & 15, ky = tid >> 4;
    float acc[7][4] = {};
    float accr[7] = {};
    for (int j = 0; j < CHB; j++) {
      float4 dv = *(const float4*)&d_s[j * 68 + (tx << 2)];
#pragma unroll
      for (int jj = 0; jj < 7; jj++) {
        int kk = ky + (jj << 4);
        if (kk < KC) {
          float rv = r_s[j * KC + kk];
          acc[jj][0] += rv * dv.x; acc[jj][1] += rv * dv.y;
          acc[jj][2] += rv * dv.z; acc[jj][3] += rv * dv.w;
          if (tx == 0) accr[jj] += rv;
        }
      }
    }
#pragma unroll
    for (int jj = 0; jj < 7; jj++) {
      int kk = ky + (jj << 4);
      if (kk < KC) {
        float* p = pcm + (size_t)blk * 6400 + kk * 64 + (tx << 2);
        p[0] = acc[jj][0]; p[1] = acc[jj][1]; p[2] = acc[jj][2]; p[3] = acc[jj][3];
        if (tx == 0) pcr[blk * KC + kk] = accr[jj];
      }
    }
  }
}

// mu[k][d] = sum_b pcm[b][k*64+d] / sum_b pcr[b][k]   (b over NPB partials)
__global__ __launch_bounds__(256) void muupd_kernel(const float* __restrict__ pcm,
    const float* __restrict__ pcr, float* __restrict__ mu,
    int it, const int* __restrict__ niter) {
  if (it > niter[0]) return;
  __shared__ float part[4][64];
  __shared__ float redc[4];
  int k = blockIdx.x, tid = threadIdx.x;
  int d = tid & 63, bg = tid >> 6;
  float s = 0.f;
  for (int b = bg; b < NPB; b += 4)
    s += pcm[(size_t)b * 6400 + k * 64 + d];
  part[bg][d] = s;
  float c = 0.f;
  for (int b = tid; b < NPB; b += 256) c += pcr[b * KC + k];
  c = wredSum(c);
  if ((tid & 63) == 0) redc[tid >> 6] = c;
  __syncthreads();
  if (tid < 64) {
    float cr = redc[0] + redc[1] + redc[2] + redc[3];
    mu[k * 64 + tid] = (part[0][tid] + part[1][tid] + part[2][tid] + part[3][tid]) / cr;
  }
}

__global__ void copy_f(const float* __restrict__ a, float* __restrict__ b, int n) {
  int i = blockIdx.x * 256 + threadIdx.x;
  if (i < n) b[i] = a[i];
}

extern "C" void kernel_launch(void* const* d_in, const int* in_sizes, int n_in,
                              void* d_out, int out_size, void* d_ws, size_t ws_size,
                              hipStream_t stream) {
  const float* x    = (const float*)d_in[0];
  const float* W1   = (const float*)d_in[1];
  const float* asr1 = (const float*)d_in[2];
  const float* ads1 = (const float*)d_in[3];
  const float* b1   = (const float*)d_in[4];
  const float* W2   = (const float*)d_in[5];
  const float* asr2 = (const float*)d_in[6];
  const float* ads2 = (const float*)d_in[7];
  const float* b2   = (const float*)d_in[8];
  const float* mu0  = (const float*)d_in[9];
  const int*   ei   = (const int*)d_in[10];
  const int*   nit  = (const int*)d_in[11];

  float* f = (float*)d_ws;
  float* h1   = f;  f += (size_t)Nn * C1;
  float* h1o  = f;  f += (size_t)Nn * C1;
  float* as1  = f;  f += Nn * 2;
  float* ad1  = f;  f += Nn * 2;
  float* h2   = f;  f += (size_t)Nn * C2;
  float* as2  = f;  f += Nn;
  float* ad2  = f;  f += Nn;
  float* dn   = f;  f += (size_t)Nn * C2;
  float* mu   = f;  f += KC * C2;
  float2* ebA = (float2*)f; f += (size_t)ETOT * 2;
  float* ebB  = (float*)ebA;            // layer-2 logits reuse layer-1 buffer
  // pcm/pcr alias h1 (dead after layer-1): 500*6400 + 500*100 = 3.25M < 5.12M floats
  float* pcm  = h1;
  float* pcr  = h1 + (size_t)NPB * 6400;
  int* ip = (int*)f;
  int* deg   = ip;  ip += Nn;
  int* rowp  = ip;  ip += Nn + 1;
  int* curs  = ip;  ip += Nn;
  int* ssort = ip;  ip += ETOT;
  int* dsort = ip;  ip += ETOT;

  float* out_mu = (float*)d_out;
  float* out_r  = out_mu + KC * C2;
  float* out_e  = out_r + (size_t)Nn * KC;
  float* out_d  = out_e + (size_t)Nn * C2;

  hipMemsetAsync(deg, 0, Nn * sizeof(int), stream);
  hist_kernel<<<(ETOT + 255) / 256, 256, 0, stream>>>(ei, deg);
  scan2_kernel<<<1, 1024, 0, stream>>>(deg, rowp, curs);
  scatter_kernel<<<(ETOT + 255) / 256, 256, 0, stream>>>(ei, curs, ssort, dsort);

  gemm1_mfma<<<dim3(157, 2), 256, 0, stream>>>(x, W1, h1);
  alpha1_kernel<<<5000, 256, 0, stream>>>(h1, asr1, ads1, as1, ad1);
  edge_e1<<<(ETOT + 255) / 256, 256, 0, stream>>>(ssort, dsort, as1, ad1, ebA);
  agg1_kernel<<<Nn, 256, 0, stream>>>(h1, ebA, ssort, b1, rowp, h1o);

  gemm_nt<<<dim3(313, 1), 256, 0, stream>>>(h1o, W2, h2, Nn, C2, C1);
  alpha2_kernel<<<5000, 256, 0, stream>>>(h2, asr2, ads2, as2, ad2);
  edge_e2<<<(ETOT + 255) / 256, 256, 0, stream>>>(ssort, dsort, as2, ad2, ebB);
  agg2_kernel<<<5000, 256, 0, stream>>>(h2, ebB, ssort, b2, rowp, out_e, dn);

  for (int it = 0; it < 12; it++) {   // device-guarded: runs niter+1 = 11 updates
    fused_ac<0><<<NPB, 256, 0, stream>>>(dn, mu0, mu, pcm, pcr, nullptr, nullptr, it, nit);
    muupd_kernel<<<KC, 256, 0, stream>>>(pcm, pcr, mu, it, nit);
  }
  fused_ac<1><<<NPB, 256, 0, stream>>>(dn, mu0, mu, nullptr, nullptr, out_r, out_d, 0, nit);
  copy_f<<<25, 256, 0, stream>>>(mu, out_mu, KC * C2);
}

// Round 8
// 1053.332 us; speedup vs baseline: 1.5871x; 1.0720x over previous
//
#include <hip/hip_runtime.h>
#include <hip/hip_bf16.h>
#include <math.h>

#define Nn 20000
#define Ee 640000
#define ETOT 660000   // Ee + Nn self loops
#define NF 512
#define C1 256        // HEADS*NHID
#define C2 64         // NOUT
#define KC 100
#define TEMP 5.0f
#define NSLOPE 0.2f
#define NPB 500       // clustering blocks
#define CHB 40        // nodes per clustering block (500*40 = 20000)

typedef __attribute__((ext_vector_type(8))) short bf16x8;
typedef __attribute__((ext_vector_type(4))) float f32x4;

__device__ __forceinline__ float wredSum(float v) {
#pragma unroll
  for (int off = 32; off > 0; off >>= 1) v += __shfl_xor(v, off, 64);
  return v;
}
__device__ __forceinline__ ushort f2bf(float f) {
  __hip_bfloat16 b = __float2bfloat16(f);
  return *(ushort*)&b;
}
__device__ __forceinline__ float bf2f(ushort u) {
  __hip_bfloat16 b = *(__hip_bfloat16*)&u;
  return __bfloat162float(b);
}

// ---------------- CSR build ----------------
__global__ void hist_kernel(const int* __restrict__ ei, int* __restrict__ deg) {
  int e = blockIdx.x * 256 + threadIdx.x;
  if (e >= ETOT) return;
  int dst = e < Ee ? ei[Ee + e] : e - Ee;
  atomicAdd(&deg[dst], 1);
}

__global__ __launch_bounds__(1024) void scan2_kernel(const int* __restrict__ deg,
    int* __restrict__ rowp, int* __restrict__ curs) {
  __shared__ int wsum[16];
  __shared__ int wpre[16];
  int t = threadIdx.x;
  int lane = t & 63, w = t >> 6;
  int loc[20];
  int tot = 0;
  int base = t * 20;
  if (t < 1000) {
#pragma unroll
    for (int i = 0; i < 20; i++) { tot += deg[base + i]; loc[i] = tot; }
  }
  int s = tot;
#pragma unroll
  for (int off = 1; off < 64; off <<= 1) {
    int u = __shfl_up(s, off, 64);
    if (lane >= off) s += u;
  }
  if (lane == 63) wsum[w] = s;
  __syncthreads();
  if (t == 0) {
    int c = 0;
#pragma unroll
    for (int i = 0; i < 16; i++) { c += wsum[i]; wpre[i] = c; }
    rowp[0] = 0;
  }
  __syncthreads();
  int p = (w > 0 ? wpre[w - 1] : 0) + s - tot;
  if (t < 1000) {
    int prev = 0;
#pragma unroll
    for (int i = 0; i < 20; i++) {
      rowp[base + i + 1] = p + loc[i];
      curs[base + i] = p + prev;
      prev = loc[i];
    }
  }
}

__global__ void scatter_kernel(const int* __restrict__ ei, int* __restrict__ curs,
                               int* __restrict__ ssort, int* __restrict__ dsort) {
  int e = blockIdx.x * 256 + threadIdx.x;
  if (e >= ETOT) return;
  int src = e < Ee ? ei[e] : e - Ee;
  int dst = e < Ee ? ei[Ee + e] : e - Ee;
  int pos = atomicAdd(&curs[dst], 1);
  ssort[pos] = src;
  dsort[pos] = dst;
}

// ---------------- per-edge logits (LeakyReLU'd), CSR order ----------------
__global__ __launch_bounds__(256) void edge_e1(const int* __restrict__ ssort,
    const int* __restrict__ dsort, const float* __restrict__ asn,
    const float* __restrict__ adn, float2* __restrict__ eb) {
  int i = blockIdx.x * 256 + threadIdx.x;
  if (i >= ETOT) return;
  int s = ssort[i], d = dsort[i];
  float2 a = ((const float2*)asn)[s];
  float2 b = ((const float2*)adn)[d];
  float e0 = a.x + b.x, e1 = a.y + b.y;
  e0 = e0 > 0.f ? e0 : NSLOPE * e0;
  e1 = e1 > 0.f ? e1 : NSLOPE * e1;
  eb[i] = make_float2(e0, e1);
}

__global__ __launch_bounds__(256) void edge_e2(const int* __restrict__ ssort,
    const int* __restrict__ dsort, const float* __restrict__ asn,
    const float* __restrict__ adn, float* __restrict__ eb) {
  int i = blockIdx.x * 256 + threadIdx.x;
  if (i >= ETOT) return;
  float e = asn[ssort[i]] + adn[dsort[i]];
  eb[i] = e > 0.f ? e : NSLOPE * e;
}

// ---------------- GEMM1 via split-bf16 MFMA (3-pass Markidis) ----------------
__global__ __launch_bounds__(256) void gemm1_mfma(const float* __restrict__ A,
    const float* __restrict__ B, float* __restrict__ C) {
  __shared__ ushort Ah[128 * 40], Al[128 * 40], Bh[128 * 40], Bl[128 * 40];
  int tid = threadIdx.x;
  int bm = blockIdx.x << 7, bn = blockIdx.y << 7;
  int w = tid >> 6, lane = tid & 63;
  int wm = (w >> 1) << 6, wn = (w & 1) << 6;
  int fr = lane & 15, ko = (lane >> 4) << 3;
  f32x4 acc[4][4] = {};
  for (int k0 = 0; k0 < 512; k0 += 32) {
    __syncthreads();
#pragma unroll
    for (int cc = 0; cc < 4; cc++) {
      int c = tid + (cc << 8);
      int row = c >> 3, q = c & 7;
      int off = row * 40 + (q << 2);
      int gr = bm + row;
      float4 va = (gr < Nn) ? *(const float4*)(A + (size_t)gr * NF + k0 + (q << 2))
                            : make_float4(0.f, 0.f, 0.f, 0.f);
      float4 vb = *(const float4*)(B + (size_t)(bn + row) * NF + k0 + (q << 2));
      ushort h0 = f2bf(va.x), h1 = f2bf(va.y), h2 = f2bf(va.z), h3 = f2bf(va.w);
      *(ushort4*)&Ah[off] = make_ushort4(h0, h1, h2, h3);
      *(ushort4*)&Al[off] = make_ushort4(
          f2bf(va.x - bf2f(h0)), f2bf(va.y - bf2f(h1)),
          f2bf(va.z - bf2f(h2)), f2bf(va.w - bf2f(h3)));
      ushort g0 = f2bf(vb.x), g1 = f2bf(vb.y), g2 = f2bf(vb.z), g3 = f2bf(vb.w);
      *(ushort4*)&Bh[off] = make_ushort4(g0, g1, g2, g3);
      *(ushort4*)&Bl[off] = make_ushort4(
          f2bf(vb.x - bf2f(g0)), f2bf(vb.y - bf2f(g1)),
          f2bf(vb.z - bf2f(g2)), f2bf(vb.w - bf2f(g3)));
    }
    __syncthreads();
    bf16x8 aH[4], bH[4], t[4];
#pragma unroll
    for (int mf = 0; mf < 4; mf++)
      aH[mf] = *(const bf16x8*)&Ah[(wm + (mf << 4) + fr) * 40 + ko];
#pragma unroll
    for (int nf = 0; nf < 4; nf++)
      bH[nf] = *(const bf16x8*)&Bh[(wn + (nf << 4) + fr) * 40 + ko];
#pragma unroll
    for (int mf = 0; mf < 4; mf++)
#pragma unroll
      for (int nf = 0; nf < 4; nf++)
        acc[mf][nf] = __builtin_amdgcn_mfma_f32_16x16x32_bf16(aH[mf], bH[nf], acc[mf][nf], 0, 0, 0);
#pragma unroll
    for (int nf = 0; nf < 4; nf++)
      t[nf] = *(const bf16x8*)&Bl[(wn + (nf << 4) + fr) * 40 + ko];
#pragma unroll
    for (int mf = 0; mf < 4; mf++)
#pragma unroll
      for (int nf = 0; nf < 4; nf++)
        acc[mf][nf] = __builtin_amdgcn_mfma_f32_16x16x32_bf16(aH[mf], t[nf], acc[mf][nf], 0, 0, 0);
#pragma unroll
    for (int mf = 0; mf < 4; mf++)
      t[mf] = *(const bf16x8*)&Al[(wm + (mf << 4) + fr) * 40 + ko];
#pragma unroll
    for (int mf = 0; mf < 4; mf++)
#pragma unroll
      for (int nf = 0; nf < 4; nf++)
        acc[mf][nf] = __builtin_amdgcn_mfma_f32_16x16x32_bf16(t[mf], bH[nf], acc[mf][nf], 0, 0, 0);
  }
  int cr = (lane >> 4) << 2, cc2 = lane & 15;
#pragma unroll
  for (int mf = 0; mf < 4; mf++) {
#pragma unroll
    for (int r = 0; r < 4; r++) {
      int row = bm + wm + (mf << 4) + cr + r;
      if (row < Nn) {
#pragma unroll
        for (int nf = 0; nf < 4; nf++)
          C[(size_t)row * C1 + bn + wn + (nf << 4) + cc2] = acc[mf][nf][r];
      }
    }
  }
}

// ---------------- f32 GEMM 64x64 (GEMM2, N=64) ----------------
__global__ __launch_bounds__(256) void gemm_nt(const float* __restrict__ A,
    const float* __restrict__ B, float* __restrict__ C, int M, int N, int K) {
  __shared__ __align__(16) float As[16][68];
  __shared__ __align__(16) float Bs[16][68];
  int tid = threadIdx.x;
  int bm = blockIdx.x << 6, bn = blockIdx.y << 6;
  int lr = tid >> 2;
  int lc = (tid & 3) << 2;
  int tx = tid & 15, ty = tid >> 4;
  float acc[4][4] = {};
  for (int k0 = 0; k0 < K; k0 += 16) {
    int am = bm + lr;
    float4 av = make_float4(0.f, 0.f, 0.f, 0.f);
    if (am < M) av = *(const float4*)(A + (size_t)am * K + k0 + lc);
    float4 bv = *(const float4*)(B + (size_t)(bn + lr) * K + k0 + lc);
    __syncthreads();
    As[lc + 0][lr] = av.x; As[lc + 1][lr] = av.y; As[lc + 2][lr] = av.z; As[lc + 3][lr] = av.w;
    Bs[lc + 0][lr] = bv.x; Bs[lc + 1][lr] = bv.y; Bs[lc + 2][lr] = bv.z; Bs[lc + 3][lr] = bv.w;
    __syncthreads();
#pragma unroll
    for (int k = 0; k < 16; k++) {
      float4 a = *(const float4*)&As[k][ty << 2];
      float4 b = *(const float4*)&Bs[k][tx << 2];
      float aa[4] = {a.x, a.y, a.z, a.w};
      float bb[4] = {b.x, b.y, b.z, b.w};
#pragma unroll
      for (int i = 0; i < 4; i++)
#pragma unroll
        for (int j = 0; j < 4; j++) acc[i][j] += aa[i] * bb[j];
    }
  }
#pragma unroll
  for (int i = 0; i < 4; i++) {
    int row = bm + (ty << 2) + i;
    if (row < M) {
#pragma unroll
      for (int j = 0; j < 4; j++)
        C[(size_t)row * N + bn + (tx << 2) + j] = acc[i][j];
    }
  }
}

// ---------------- per-node attention scalars ----------------
__global__ __launch_bounds__(256) void alpha1_kernel(const float* __restrict__ h,
    const float* __restrict__ a_src, const float* __restrict__ a_dst,
    float* __restrict__ asn, float* __restrict__ adn) {
  int l = threadIdx.x & 63;
  int n = (blockIdx.x << 2) + (threadIdx.x >> 6);
  if (n >= Nn) return;
  const float* hr = h + (size_t)n * C1;
  float h0 = hr[l], h1v = hr[64 + l], h2v = hr[128 + l], h3v = hr[192 + l];
  float ps0 = h0 * a_src[l] + h1v * a_src[64 + l];
  float pd0 = h0 * a_dst[l] + h1v * a_dst[64 + l];
  float ps1 = h2v * a_src[128 + l] + h3v * a_src[192 + l];
  float pd1 = h2v * a_dst[128 + l] + h3v * a_dst[192 + l];
  ps0 = wredSum(ps0); pd0 = wredSum(pd0); ps1 = wredSum(ps1); pd1 = wredSum(pd1);
  if (l == 0) {
    asn[2 * n] = ps0; asn[2 * n + 1] = ps1;
    adn[2 * n] = pd0; adn[2 * n + 1] = pd1;
  }
}

__global__ __launch_bounds__(256) void alpha2_kernel(const float* __restrict__ h,
    const float* __restrict__ a_src, const float* __restrict__ a_dst,
    float* __restrict__ asn, float* __restrict__ adn) {
  int l = threadIdx.x & 63;
  int n = (blockIdx.x << 2) + (threadIdx.x >> 6);
  if (n >= Nn) return;
  float v = h[(size_t)n * C2 + l];
  float ps = wredSum(v * a_src[l]);
  float pd = wredSum(v * a_dst[l]);
  if (l == 0) { asn[n] = ps; adn[n] = pd; }
}

// ---------------- layer 1: online segment softmax + float4 gather + ELU ----------------
__global__ __launch_bounds__(256) void agg1_kernel(const float* __restrict__ h,
    const float2* __restrict__ eb, const int* __restrict__ ssort,
    const float* __restrict__ b1, const int* __restrict__ rowp,
    float* __restrict__ ho) {
  __shared__ float redm[8], reds[8];
  __shared__ __align__(16) float slab[4][256];
  int n = blockIdx.x, tid = threadIdx.x;
  int w = tid >> 6, l = tid & 63;
  int lo = rowp[n], hi = rowp[n + 1];
  float m0 = -1e30f, s0 = 0.f, m1 = -1e30f, s1 = 0.f;
  for (int i = lo + tid; i < hi; i += 256) {
    float2 e = eb[i];
    if (e.x > m0) { s0 = s0 * __expf(m0 - e.x) + 1.f; m0 = e.x; }
    else s0 += __expf(e.x - m0);
    if (e.y > m1) { s1 = s1 * __expf(m1 - e.y) + 1.f; m1 = e.y; }
    else s1 += __expf(e.y - m1);
  }
#pragma unroll
  for (int off = 32; off > 0; off >>= 1) {
    float om = __shfl_xor(m0, off, 64), os = __shfl_xor(s0, off, 64);
    float nm = fmaxf(m0, om);
    s0 = s0 * __expf(m0 - nm) + os * __expf(om - nm); m0 = nm;
    om = __shfl_xor(m1, off, 64); os = __shfl_xor(s1, off, 64);
    nm = fmaxf(m1, om);
    s1 = s1 * __expf(m1 - nm) + os * __expf(om - nm); m1 = nm;
  }
  if (l == 0) { redm[w] = m0; reds[w] = s0; redm[4 + w] = m1; reds[4 + w] = s1; }
  __syncthreads();
  float M0 = fmaxf(fmaxf(redm[0], redm[1]), fmaxf(redm[2], redm[3]));
  float M1 = fmaxf(fmaxf(redm[4], redm[5]), fmaxf(redm[6], redm[7]));
  float S0 = reds[0] * __expf(redm[0] - M0) + reds[1] * __expf(redm[1] - M0)
           + reds[2] * __expf(redm[2] - M0) + reds[3] * __expf(redm[3] - M0);
  float S1 = reds[4] * __expf(redm[4] - M1) + reds[5] * __expf(redm[5] - M1)
           + reds[6] * __expf(redm[6] - M1) + reds[7] * __expf(redm[7] - M1);
  float inv0 = 1.f / (S0 + 1e-16f), inv1 = 1.f / (S1 + 1e-16f);
  const bool lo_head = (l < 32);
  float Msel = lo_head ? M0 : M1;
  float isel = lo_head ? inv0 : inv1;
  int ch = l << 2;
  int deg = hi - lo;
  float4 accA = {0.f, 0.f, 0.f, 0.f}, accB = {0.f, 0.f, 0.f, 0.f};
  int j = w;
  for (; j + 4 < deg; j += 8) {
    int i0 = lo + j, i1 = lo + j + 4;
    float2 eA = eb[i0];
    float2 eB = eb[i1];
    int sA = ssort[i0], sB = ssort[i1];
    float4 ha = *(const float4*)(h + (size_t)sA * C1 + ch);
    float4 hb = *(const float4*)(h + (size_t)sB * C1 + ch);
    float wtA = __expf((lo_head ? eA.x : eA.y) - Msel) * isel;
    float wtB = __expf((lo_head ? eB.x : eB.y) - Msel) * isel;
    accA.x += wtA * ha.x; accA.y += wtA * ha.y; accA.z += wtA * ha.z; accA.w += wtA * ha.w;
    accB.x += wtB * hb.x; accB.y += wtB * hb.y; accB.z += wtB * hb.z; accB.w += wtB * hb.w;
  }
  if (j < deg) {
    int i0 = lo + j;
    float2 eA = eb[i0];
    int sA = ssort[i0];
    float4 ha = *(const float4*)(h + (size_t)sA * C1 + ch);
    float wtA = __expf((lo_head ? eA.x : eA.y) - Msel) * isel;
    accA.x += wtA * ha.x; accA.y += wtA * ha.y; accA.z += wtA * ha.z; accA.w += wtA * ha.w;
  }
  accA.x += accB.x; accA.y += accB.y; accA.z += accB.z; accA.w += accB.w;
  *(float4*)&slab[w][ch] = accA;
  __syncthreads();
  float v = slab[0][tid] + slab[1][tid] + slab[2][tid] + slab[3][tid] + b1[tid];
  ho[(size_t)n * C1 + tid] = v > 0.f ? v : __expf(v) - 1.0f;   // ELU
}

// ---------------- layer 2: wave-per-node, fused softmax+gather+normalize ----------------
__global__ __launch_bounds__(256) void agg2_kernel(const float* __restrict__ h,
    const float* __restrict__ eb, const int* __restrict__ ssort,
    const float* __restrict__ b2, const int* __restrict__ rowp,
    float* __restrict__ emb, float* __restrict__ dnrm) {
  int tid = threadIdx.x;
  int w = tid >> 6, l = tid & 63;
  int n = (blockIdx.x << 2) + w;
  int lo = rowp[n], hi = rowp[n + 1];
  float m = -1e30f, s = 0.f;
  for (int i = lo + l; i < hi; i += 64) {
    float e = eb[i];
    if (e > m) { s = s * __expf(m - e) + 1.f; m = e; }
    else s += __expf(e - m);
  }
#pragma unroll
  for (int off = 32; off > 0; off >>= 1) {
    float om = __shfl_xor(m, off, 64), os = __shfl_xor(s, off, 64);
    float nm = fmaxf(m, om);
    s = s * __expf(m - nm) + os * __expf(om - nm); m = nm;
  }
  float inv = 1.f / (s + 1e-16f);
  int g = l >> 4, lg = l & 15, ch = lg << 2;
  int deg = hi - lo;
  float4 accA = {0.f, 0.f, 0.f, 0.f}, accB = {0.f, 0.f, 0.f, 0.f};
  int j = g;
  for (; j + 4 < deg; j += 8) {
    int i0 = lo + j, i1 = lo + j + 4;
    float eA = eb[i0], eB = eb[i1];
    int sA = ssort[i0], sB = ssort[i1];
    float4 ha = *(const float4*)(h + (size_t)sA * C2 + ch);
    float4 hb = *(const float4*)(h + (size_t)sB * C2 + ch);
    float wtA = __expf(eA - m) * inv;
    float wtB = __expf(eB - m) * inv;
    accA.x += wtA * ha.x; accA.y += wtA * ha.y; accA.z += wtA * ha.z; accA.w += wtA * ha.w;
    accB.x += wtB * hb.x; accB.y += wtB * hb.y; accB.z += wtB * hb.z; accB.w += wtB * hb.w;
  }
  if (j < deg) {
    int i0 = lo + j;
    float eA = eb[i0];
    int sA = ssort[i0];
    float4 ha = *(const float4*)(h + (size_t)sA * C2 + ch);
    float wtA = __expf(eA - m) * inv;
    accA.x += wtA * ha.x; accA.y += wtA * ha.y; accA.z += wtA * ha.z; accA.w += wtA * ha.w;
  }
  accA.x += accB.x; accA.y += accB.y; accA.z += accB.z; accA.w += accB.w;
#pragma unroll
  for (int off = 16; off <= 32; off <<= 1) {
    accA.x += __shfl_xor(accA.x, off, 64);
    accA.y += __shfl_xor(accA.y, off, 64);
    accA.z += __shfl_xor(accA.z, off, 64);
    accA.w += __shfl_xor(accA.w, off, 64);
  }
  float4 bv = *(const float4*)(b2 + ch);
  float e0 = accA.x + bv.x + 1e-6f;
  float e1 = accA.y + bv.y + 1e-6f;
  float e2 = accA.z + bv.z + 1e-6f;
  float e3 = accA.w + bv.w + 1e-6f;
  float dot = e0 * e0 + e1 * e1 + e2 * e2 + e3 * e3;
#pragma unroll
  for (int off = 1; off < 16; off <<= 1) dot += __shfl_xor(dot, off, 64);
  float invn = 1.f / sqrtf(dot);
  if (g == 0) {
    *(float4*)(emb + (size_t)n * C2 + ch) = make_float4(e0, e1, e2, e3);
    *(float4*)(dnrm + (size_t)n * C2 + ch) =
        make_float4(e0 * invn, e1 * invn, e2 * invn, e3 * invn);
  }
}

// ---------------- clustering: fused assign (+partial cmean), vectorized LDS ----------------
// 500 blocks x 40 nodes. Assign: dq-outer loop, 20 f32 accumulators, b128 LDS reads.
// cmean: (k-quad x d-quad) mapping, b128 reads, outer-product FMA.
template <int MODE>
__global__ __launch_bounds__(256) void fused_ac(
    const float* __restrict__ dnp, const float* __restrict__ mu_init,
    const float* __restrict__ mu, float* __restrict__ pcm, float* __restrict__ pcr,
    float* __restrict__ rout, float* __restrict__ distout,
    int it, const int* __restrict__ niter) {
  if (MODE == 0) { if (it > niter[0]) return; }
  __shared__ __align__(16) float mu_s[KC * 68];   // stride 68 words: 16B-aligned rows
  __shared__ __align__(16) float d_s[CHB * 64];   // stride 64 (broadcast/quad reads)
  __shared__ __align__(16) float r_s[CHB * KC];   // [node][k], stride 100 (16B-aligned)
  int tid = threadIdx.x, blk = blockIdx.x;
  const float* msrc = (MODE == 0 && it == 0) ? mu_init : mu;
  for (int idx = tid; idx < KC * 64; idx += 256)
    mu_s[(idx >> 6) * 68 + (idx & 63)] = msrc[idx];
  for (int idx = tid; idx < CHB * 64; idx += 256)
    d_s[idx] = dnp[(size_t)blk * (CHB * 64) + idx];
  __syncthreads();
  int w = tid >> 6, l = tid & 63;
  const bool has2 = l < (KC - 64);
  int l2 = has2 ? 64 + l : l;
  int nbase = w * 10;
  float z1[5][2] = {}, z2[5][2] = {};
#pragma unroll 4
  for (int dq = 0; dq < 16; dq++) {
    float4 m1 = *(const float4*)&mu_s[l * 68 + (dq << 2)];
    float4 m2 = *(const float4*)&mu_s[l2 * 68 + (dq << 2)];
#pragma unroll
    for (int g = 0; g < 5; g++) {
#pragma unroll
      for (int nb = 0; nb < 2; nb++) {
        float4 dv = *(const float4*)&d_s[(nbase + g * 2 + nb) * 64 + (dq << 2)];
        z1[g][nb] += m1.x * dv.x + m1.y * dv.y + m1.z * dv.z + m1.w * dv.w;
        z2[g][nb] += m2.x * dv.x + m2.y * dv.y + m2.z * dv.z + m2.w * dv.w;
      }
    }
  }
#pragma unroll
  for (int g = 0; g < 5; g++) {
#pragma unroll
    for (int nb = 0; nb < 2; nb++) {
      float e1 = __expf(TEMP * z1[g][nb]);
      float e2 = has2 ? __expf(TEMP * z2[g][nb]) : 0.f;
      float inv = 1.0f / wredSum(e1 + e2);
      int nl = nbase + g * 2 + nb;
      if (MODE == 0) {
        r_s[nl * KC + l] = e1 * inv;
        if (has2) r_s[nl * KC + 64 + l] = e2 * inv;
      } else {
        size_t n = (size_t)blk * CHB + nl;
        rout[n * KC + l] = e1 * inv;
        if (has2) rout[n * KC + 64 + l] = e2 * inv;
        distout[n * KC + l] = z1[g][nb];
        if (has2) distout[n * KC + 64 + l] = z2[g][nb];
      }
    }
  }
  if (MODE == 0) {
    __syncthreads();
    int tx = tid & 15, ky = tid >> 4;        // tx: d-quad, ky: k-quad
    const bool two = (ky < 9);               // k-quads 16..24
    int kq0 = ky, kq1 = 16 + ky;
    float a0[4][4] = {}, a1[4][4] = {};
    float ar0[4] = {}, ar1[4] = {};
#pragma unroll 2
    for (int j = 0; j < CHB; j++) {
      float4 dv = *(const float4*)&d_s[j * 64 + (tx << 2)];
      float4 r0 = *(const float4*)&r_s[j * KC + (kq0 << 2)];
      float rv0[4] = {r0.x, r0.y, r0.z, r0.w};
#pragma unroll
      for (int i = 0; i < 4; i++) {
        a0[i][0] += rv0[i] * dv.x; a0[i][1] += rv0[i] * dv.y;
        a0[i][2] += rv0[i] * dv.z; a0[i][3] += rv0[i] * dv.w;
      }
      if (tx == 0) { ar0[0] += r0.x; ar0[1] += r0.y; ar0[2] += r0.z; ar0[3] += r0.w; }
      if (two) {
        float4 r1 = *(const float4*)&r_s[j * KC + (kq1 << 2)];
        float rv1[4] = {r1.x, r1.y, r1.z, r1.w};
#pragma unroll
        for (int i = 0; i < 4; i++) {
          a1[i][0] += rv1[i] * dv.x; a1[i][1] += rv1[i] * dv.y;
          a1[i][2] += rv1[i] * dv.z; a1[i][3] += rv1[i] * dv.w;
        }
        if (tx == 0) { ar1[0] += r1.x; ar1[1] += r1.y; ar1[2] += r1.z; ar1[3] += r1.w; }
      }
    }
#pragma unroll
    for (int i = 0; i < 4; i++) {
      *(float4*)&pcm[(size_t)blk * 6400 + (kq0 * 4 + i) * 64 + (tx << 2)] =
          make_float4(a0[i][0], a0[i][1], a0[i][2], a0[i][3]);
      if (two)
        *(float4*)&pcm[(size_t)blk * 6400 + (kq1 * 4 + i) * 64 + (tx << 2)] =
            make_float4(a1[i][0], a1[i][1], a1[i][2], a1[i][3]);
    }
    if (tx == 0) {
      *(float4*)&pcr[(size_t)blk * KC + kq0 * 4] = make_float4(ar0[0], ar0[1], ar0[2], ar0[3]);
      if (two)
        *(float4*)&pcr[(size_t)blk * KC + kq1 * 4] = make_float4(ar1[0], ar1[1], ar1[2], ar1[3]);
    }
  }
}

// mu[k][d] = sum_b pcm[b][k*64+d] / sum_b pcr[b][k]   (b over NPB partials)
__global__ __launch_bounds__(256) void muupd_kernel(const float* __restrict__ pcm,
    const float* __restrict__ pcr, float* __restrict__ mu,
    int it, const int* __restrict__ niter) {
  if (it > niter[0]) return;
  __shared__ float part[4][64];
  __shared__ float redc[4];
  int k = blockIdx.x, tid = threadIdx.x;
  int d = tid & 63, bg = tid >> 6;
  float s = 0.f;
  for (int b = bg; b < NPB; b += 4)
    s += pcm[(size_t)b * 6400 + k * 64 + d];
  part[bg][d] = s;
  float c = 0.f;
  for (int b = tid; b < NPB; b += 256) c += pcr[b * KC + k];
  c = wredSum(c);
  if ((tid & 63) == 0) redc[tid >> 6] = c;
  __syncthreads();
  if (tid < 64) {
    float cr = redc[0] + redc[1] + redc[2] + redc[3];
    mu[k * 64 + tid] = (part[0][tid] + part[1][tid] + part[2][tid] + part[3][tid]) / cr;
  }
}

__global__ void copy_f(const float* __restrict__ a, float* __restrict__ b, int n) {
  int i = blockIdx.x * 256 + threadIdx.x;
  if (i < n) b[i] = a[i];
}

extern "C" void kernel_launch(void* const* d_in, const int* in_sizes, int n_in,
                              void* d_out, int out_size, void* d_ws, size_t ws_size,
                              hipStream_t stream) {
  const float* x    = (const float*)d_in[0];
  const float* W1   = (const float*)d_in[1];
  const float* asr1 = (const float*)d_in[2];
  const float* ads1 = (const float*)d_in[3];
  const float* b1   = (const float*)d_in[4];
  const float* W2   = (const float*)d_in[5];
  const float* asr2 = (const float*)d_in[6];
  const float* ads2 = (const float*)d_in[7];
  const float* b2   = (const float*)d_in[8];
  const float* mu0  = (const float*)d_in[9];
  const int*   ei   = (const int*)d_in[10];
  const int*   nit  = (const int*)d_in[11];

  float* f = (float*)d_ws;
  float* h1   = f;  f += (size_t)Nn * C1;
  float* h1o  = f;  f += (size_t)Nn * C1;
  float* as1  = f;  f += Nn * 2;
  float* ad1  = f;  f += Nn * 2;
  float* h2   = f;  f += (size_t)Nn * C2;
  float* as2  = f;  f += Nn;
  float* ad2  = f;  f += Nn;
  float* dn   = f;  f += (size_t)Nn * C2;
  float* mu   = f;  f += KC * C2;
  float2* ebA = (float2*)f; f += (size_t)ETOT * 2;
  float* ebB  = (float*)ebA;            // layer-2 logits reuse layer-1 buffer
  // pcm/pcr alias h1 (dead after layer-1): 500*6400 + 500*100 = 3.25M < 5.12M floats
  float* pcm  = h1;
  float* pcr  = h1 + (size_t)NPB * 6400;
  int* ip = (int*)f;
  int* deg   = ip;  ip += Nn;
  int* rowp  = ip;  ip += Nn + 1;
  int* curs  = ip;  ip += Nn;
  int* ssort = ip;  ip += ETOT;
  int* dsort = ip;  ip += ETOT;

  float* out_mu = (float*)d_out;
  float* out_r  = out_mu + KC * C2;
  float* out_e  = out_r + (size_t)Nn * KC;
  float* out_d  = out_e + (size_t)Nn * C2;

  hipMemsetAsync(deg, 0, Nn * sizeof(int), stream);
  hist_kernel<<<(ETOT + 255) / 256, 256, 0, stream>>>(ei, deg);
  scan2_kernel<<<1, 1024, 0, stream>>>(deg, rowp, curs);
  scatter_kernel<<<(ETOT + 255) / 256, 256, 0, stream>>>(ei, curs, ssort, dsort);

  gemm1_mfma<<<dim3(157, 2), 256, 0, stream>>>(x, W1, h1);
  alpha1_kernel<<<5000, 256, 0, stream>>>(h1, asr1, ads1, as1, ad1);
  edge_e1<<<(ETOT + 255) / 256, 256, 0, stream>>>(ssort, dsort, as1, ad1, ebA);
  agg1_kernel<<<Nn, 256, 0, stream>>>(h1, ebA, ssort, b1, rowp, h1o);

  gemm_nt<<<dim3(313, 1), 256, 0, stream>>>(h1o, W2, h2, Nn, C2, C1);
  alpha2_kernel<<<5000, 256, 0, stream>>>(h2, asr2, ads2, as2, ad2);
  edge_e2<<<(ETOT + 255) / 256, 256, 0, stream>>>(ssort, dsort, as2, ad2, ebB);
  agg2_kernel<<<5000, 256, 0, stream>>>(h2, ebB, ssort, b2, rowp, out_e, dn);

  for (int it = 0; it < 12; it++) {   // device-guarded: runs niter+1 = 11 updates
    fused_ac<0><<<NPB, 256, 0, stream>>>(dn, mu0, mu, pcm, pcr, nullptr, nullptr, it, nit);
    muupd_kernel<<<KC, 256, 0, stream>>>(pcm, pcr, mu, it, nit);
  }
  fused_ac<1><<<NPB, 256, 0, stream>>>(dn, mu0, mu, nullptr, nullptr, out_r, out_d, 0, nit);
  copy_f<<<25, 256, 0, stream>>>(mu, out_mu, KC * C2);
}